// Round 1
// 168.072 us; speedup vs baseline: 1.0592x; 1.0592x over previous
//
#include <hip/hip_runtime.h>
#include <cstdint>

#define N 8192
#define NT 128      // 64-col chunks per row (N/64)
#define R_ASYNC 16  // in-kernel async classification rounds (correctness-independent)
typedef unsigned long long u64;
typedef unsigned int u32;

// ---------------------------------------------------------------------------
// K1: rank by counting, keys recomputed inline from scores (descending score,
// stable ascending index). Partial counts per y-slab -> rankpart[8][N]; no
// atomics, no zero-init kernel needed.
// ---------------------------------------------------------------------------
__global__ __launch_bounds__(256) void k_rank(const float* __restrict__ scores,
                                              int* __restrict__ rankpart) {
  __shared__ u64 tile[1024];
  int e = blockIdx.x * 256 + threadIdx.x;
  int j0 = blockIdx.y * 1024;
  for (int t = threadIdx.x; t < 1024; t += 256) {
    int j = j0 + t;
    tile[t] = ((u64)__float_as_uint(scores[j]) << 32) | (unsigned)(0xFFFFFFFFu - (unsigned)j);
  }
  __syncthreads();
  u64 ke = ((u64)__float_as_uint(scores[e]) << 32) | (unsigned)(0xFFFFFFFFu - (unsigned)e);
  int c = 0;
#pragma unroll 8
  for (int k = 0; k < 1024; ++k) c += (tile[k] > ke) ? 1 : 0;
  rankpart[blockIdx.y * N + e] = c;
}

// ---------------------------------------------------------------------------
// K2: sum rank partials + scatter into sorted SoA (clipped coords, score,
// area) + init all aux state (cnt, prob, packed-first, D, S).
// ---------------------------------------------------------------------------
__global__ __launch_bounds__(256) void k_scatter(const float* __restrict__ boxes,
                                                 const float* __restrict__ scores,
                                                 const int* __restrict__ rankpart,
                                                 float* __restrict__ bx1s, float* __restrict__ by1s,
                                                 float* __restrict__ bx2s, float* __restrict__ by2s,
                                                 float* __restrict__ ss, float* __restrict__ areas,
                                                 int* __restrict__ cnt,
                                                 float* __restrict__ prob,
                                                 u64* __restrict__ pk,
                                                 u64* __restrict__ D,
                                                 u64* __restrict__ S) {
#pragma clang fp contract(off)
  int i = blockIdx.x * 256 + threadIdx.x;
  if (i >= N) return;
  int r = 0;
#pragma unroll
  for (int q = 0; q < 8; ++q) r += rankpart[q * N + i];
  float x1 = fminf(fmaxf(boxes[i * 4 + 0], 0.0f), 1920.0f);
  float y1 = fminf(fmaxf(boxes[i * 4 + 1], 0.0f), 1080.0f);
  float x2 = fminf(fmaxf(boxes[i * 4 + 2], 0.0f), 1920.0f);
  float y2 = fminf(fmaxf(boxes[i * 4 + 3], 0.0f), 1080.0f);
  bx1s[r] = x1; by1s[r] = y1; bx2s[r] = x2; by2s[r] = y2;
  ss[r] = scores[i];
  areas[r] = (x2 - x1 + 1.0f) * (y2 - y1 + 1.0f);
  cnt[i] = 0;
  prob[i] = 0.0f;
  pk[i] = 0ull;
  if (i < NT) { D[i] = 0ull; S[i] = 0ull; }
}

// ---------------------------------------------------------------------------
// K3: adjacency, SYMMETRIC lower-triangle blocks + ballot transpose.
// Band trick (verified absmax 0.0): iou>0.5 <=> 2*inter>uni whenever
// |2*inter-uni| > 1e-6*uni (RN div error <= 3e-8 rel << band margin); only
// in-band lanes take the exact IEEE divide, ballot-guarded.
// fp contract OFF everywhere; matrix float-exact symmetric.
// ---------------------------------------------------------------------------
__global__ __launch_bounds__(64) void k_adj(const float* __restrict__ bx1s, const float* __restrict__ by1s,
                                            const float* __restrict__ bx2s, const float* __restrict__ by2s,
                                            const float* __restrict__ areas,
                                            u64* __restrict__ mtile,
                                            u64* __restrict__ mrow) {
#pragma clang fp contract(off)
  __shared__ float jx1[64], jy1[64], jx2[64], jy2[64], ja[64];
  int p = blockIdx.x;
  int gy = (int)((sqrtf(8.0f * (float)p + 1.0f) - 1.0f) * 0.5f);
  while ((gy + 1) * (gy + 2) / 2 <= p) ++gy;
  while (gy * (gy + 1) / 2 > p) --gy;
  int gx = p - gy * (gy + 1) / 2;

  int l = threadIdx.x;
  int j = gx * 64 + l;
  jx1[l] = bx1s[j]; jy1[l] = by1s[j]; jx2[l] = bx2s[j]; jy2[l] = by2s[j]; ja[l] = areas[j];
  __syncthreads();
  int i = gy * 64 + l;
  float x1 = bx1s[i], y1 = by1s[i], x2 = bx2s[i], y2 = by2s[i], ai = areas[i];
  u64 bits = 0;
#pragma unroll 4
  for (int jj = 0; jj < 64; ++jj) {
    float ix1 = fmaxf(x1, jx1[jj]);
    float iy1 = fmaxf(y1, jy1[jj]);
    float ix2 = fminf(x2, jx2[jj]);
    float iy2 = fminf(y2, jy2[jj]);
    float iw = fmaxf(ix2 - ix1 + 1.0f, 0.0f);
    float ih = fmaxf(iy2 - iy1 + 1.0f, 0.0f);
    float inter = iw * ih;
    float uni = (ai + ja[jj]) - inter;   // uni > 0 always (areas >= 1)
    float t = inter + inter;             // exact (x2)
    bool gt = t > uni;
    bool amb = fabsf(t - uni) <= 1e-6f * uni;
    if (__ballot(amb) != 0ull) {         // ~never taken
      float iou = inter / uni;           // exact IEEE div, matches numpy
      if (amb) gt = iou > 0.5f;
    }
    bits |= ((u64)gt) << jj;
  }
  mtile[((size_t)gy * NT + gx) * 64 + l] = bits;
  mrow[(size_t)i * NT + gx] = bits;
  if (gx != gy) {
    u64 tb = 0;
#pragma unroll 8
    for (int c = 0; c < 64; ++c) {
      u64 wb = __ballot((bits >> c) & 1ull);
      tb = (l == c) ? wb : tb;
    }
    mtile[((size_t)gx * NT + gy) * 64 + l] = tb;
    mrow[(size_t)(gx * 64 + l) * NT + gy] = tb;
  }
}

// ---------------------------------------------------------------------------
// K4: ALL classification rounds in ONE launch. Each block owns row gy and
// iterates R_ASYNC monotone rounds, re-reading D/S via device-scope atomic
// loads (cross-XCD visible). Soundness does not depend on synchronization:
// stale D is a subset of true heads (suppress rule conservative), stale S a
// subset of true suppressed (head rule conservative) -> any interleaving only
// DELAYS classification, never corrupts. k_fix is exact for any round state.
// Async iteration (~1us feedback) converges further than 8 separate launches
// (~5us/launch), shrinking k_fix's serial M.
// ---------------------------------------------------------------------------
__global__ __launch_bounds__(256) void k_rounds(const u64* __restrict__ mtile,
                                                u64* __restrict__ D,
                                                u64* __restrict__ S) {
  __shared__ u64 Dl[NT], Sl[NT];
  __shared__ u64 bw[2][4];
  int gy = blockIdx.x;
  int t = threadIdx.x;
  int w = t >> 6, r = t & 63;
  for (int it = 0; it < R_ASYNC; ++it) {
    if (t < NT)
      Dl[t] = __hip_atomic_load(&D[t], __ATOMIC_RELAXED, __HIP_MEMORY_SCOPE_AGENT);
    else
      Sl[t - NT] = __hip_atomic_load(&S[t - NT], __ATOMIC_RELAXED, __HIP_MEMORY_SCOPE_AGENT);
    __syncthreads();
    u64 classified = Dl[gy] | Sl[gy];
    if (classified == ~0ull) return;   // row done (uniform across block)
    bool unk = !((classified >> r) & 1ull);
    u64 anyD = 0, anyU = 0;
    if (unk) {
      int k0 = 32 * w, k1 = min(k0 + 32, gy + 1);
      for (int k = k0; k < k1; ++k) {
        u64 m = mtile[((size_t)gy * NT + k) * 64 + r];
        if (k == gy) m &= (1ull << r) - 1ull;   // strictly earlier within own tile
        anyD |= (m & Dl[k]);
        anyU |= (m & ~Sl[k]);
      }
    }
    u64 bD = __ballot(anyD != 0ull), bU = __ballot(anyU != 0ull);
    if (r == 0) { bw[0][w] = bD; bw[1][w] = bU; }
    __syncthreads();
    if (t == 0) {
      u64 rD = bw[0][0] | bw[0][1] | bw[0][2] | bw[0][3];
      u64 rU = bw[1][0] | bw[1][1] | bw[1][2] | bw[1][3];
      u64 unkb = ~classified;
      u64 newS = unkb & rD;
      u64 newD = unkb & ~rD & ~rU;
      if (newS) atomicOr(&S[gy], newS);
      if (newD) atomicOr(&D[gy], newD);
    }
    __syncthreads();   // protect Dl/Sl/bw reuse across iterations
  }
}

// ---------------------------------------------------------------------------
// K5: exact serial cleanup, ONE wave, BRANCHLESS inner loop (~25-30cy per
// unknown on the serial chain). Invariant: when row j is tested, D contains
// ALL true heads < j, so (row_j & D & below) == 0 <=> j is a head. Exact for
// ANY round state. Rows fetched coalesced (1 KB) via 8-deep register ring.
// ---------------------------------------------------------------------------
__global__ __launch_bounds__(64, 1) void k_fix(const u64* __restrict__ mrow,
                                               u64* __restrict__ D,
                                               const u64* __restrict__ S) {
  __shared__ int ulist[N];
  int l = threadIdx.x;
  u64 D0 = D[2 * l], D1 = D[2 * l + 1];
  u64 S0 = S[2 * l], S1 = S[2 * l + 1];
  u64 u0 = ~(D0 | S0), u1 = ~(D1 | S1);
  int cnt = __popcll(u0) + __popcll(u1);
  int pre = cnt;
  for (int d = 1; d < 64; d <<= 1) {
    int v = __shfl_up(pre, d);
    if (l >= d) pre += v;
  }
  int M = __shfl(pre, 63);
  int off = pre - cnt;
  {
    u64 v = u0; int o = off;
    while (v) { int b = __builtin_ctzll(v); v &= v - 1; ulist[o++] = l * 128 + b; }
    v = u1;
    while (v) { int b = __builtin_ctzll(v); v &= v - 1; ulist[o++] = l * 128 + 64 + b; }
  }
  __syncthreads();
  if (M > 0) {
    ulong2 ring[8];
    int pj[8];
#pragma unroll
    for (int q = 0; q < 8; ++q) {
      int j = ulist[q < M ? q : M - 1];
      pj[q] = j;
      ring[q] = *(const ulong2*)&mrow[(size_t)j * NT + 2 * l];
    }
    for (int m = 0; m < M; ++m) {
      int slot = m & 7;
      int j = pj[slot];
      ulong2 rv = ring[slot];
      int jt = j >> 6;                       // uniform
      u64 bm = (1ull << (j & 63)) - 1ull;
      u64 m0 = (2 * l < jt) ? ~0ull : ((2 * l == jt) ? bm : 0ull);
      u64 m1 = (2 * l + 1 < jt) ? ~0ull : ((2 * l + 1 == jt) ? bm : 0ull);
      bool hit = ((rv.x & D0 & m0) | (rv.y & D1 & m1)) != 0ull;
      bool head = (__ballot(hit) == 0ull);   // uniform
      u64 bset = 1ull << (j & 63);
      D0 |= (head && (2 * l == jt)) ? bset : 0ull;       // branchless update
      D1 |= (head && (2 * l + 1 == jt)) ? bset : 0ull;
      int nm = m + 8;
      int j2 = ulist[nm < M ? nm : M - 1];
      pj[slot] = j2;
      ring[slot] = *(const ulong2*)&mrow[(size_t)j2 * NT + 2 * l];
    }
  }
  D[2 * l] = D0;
  D[2 * l + 1] = D1;
}

// ---------------------------------------------------------------------------
// K6: parallel cluster assignment + segment atomics. cluster[j] = first head
// adjacent to j; that head index is provably <= j (j self-adjacent if head,
// else suppressed by an earlier adjacent head) -> scan only tiles k <= gy.
// Fused "first index at cluster-max y2" via ONE packed u64 atomicMax:
// (y2_bits << 32) | ~j  -- y2 >= 0 so uint order == float order; tie -> min j,
// exactly the reference's segment_min over cand = (y2 >= segmax).
// ---------------------------------------------------------------------------
__global__ __launch_bounds__(256) void k_cluster(const u64* __restrict__ mtile,
                                                 const u64* __restrict__ D,
                                                 const float* __restrict__ ss,
                                                 const float* __restrict__ by2s,
                                                 int* __restrict__ cluster,
                                                 int* __restrict__ cnt,
                                                 float* __restrict__ prob,
                                                 u64* __restrict__ pk) {
  __shared__ u64 hlds[NT];
  __shared__ int red[4][64];
  int gy = blockIdx.x;
  if (threadIdx.x < NT) hlds[threadIdx.x] = D[threadIdx.x];
  __syncthreads();
  int w = threadIdx.x >> 6, r = threadIdx.x & 63;
  int best = 0x7fffffff;
  for (int k = w; k <= gy; k += 4) {      // per-group candidates ascend with k
    u64 v = mtile[((size_t)gy * NT + k) * 64 + r] & hlds[k];
    if (v) { best = k * 64 + __builtin_ctzll(v); break; }
  }
  red[w][r] = best;
  __syncthreads();
  if (w == 0) {
    int b = min(min(red[0][r], red[1][r]), min(red[2][r], red[3][r]));
    int j = gy * 64 + r;
    cluster[j] = b;
    atomicAdd(&cnt[b], 1);
    atomicAdd(&prob[b], ss[j]);
    atomicMax((unsigned long long*)&pk[b],
              ((u64)__float_as_uint(by2s[j]) << 32) | (u64)(0xFFFFFFFFu - (unsigned)j));
  }
}

// ---------------------------------------------------------------------------
// K7: outputs. out[j][0..4] then keep[j] appended (floats 0/1).
// first index recovered from packed atomicMax: ~low32(pk).
// ---------------------------------------------------------------------------
__global__ __launch_bounds__(256) void k_out(const int* __restrict__ cluster,
                                             const float* __restrict__ bx1s, const float* __restrict__ by1s,
                                             const float* __restrict__ bx2s, const float* __restrict__ by2s,
                                             const int* __restrict__ cnt,
                                             const float* __restrict__ prob,
                                             const u64* __restrict__ pk,
                                             const int* __restrict__ num_models,
                                             float* __restrict__ out) {
  int j = blockIdx.x * 256 + threadIdx.x;
  if (j >= N) return;
  int c = cluster[j];
  int nm = num_models[0];
  bool valid = (float)cnt[c] >= (float)nm / 3.0f;
  unsigned fj = 0xFFFFFFFFu - (unsigned)(pk[c] & 0xFFFFFFFFull);
  bool keep = (fj == (unsigned)j) && valid;
  float o0 = 0.f, o1 = 0.f, o2 = 0.f, o3 = 0.f, o4 = 0.f;
  if (keep) {
    o0 = bx1s[j]; o1 = by1s[j]; o2 = bx2s[j]; o3 = by2s[j];
    o4 = prob[c] / (float)nm;
  }
  out[j * 5 + 0] = o0;
  out[j * 5 + 1] = o1;
  out[j * 5 + 2] = o2;
  out[j * 5 + 3] = o3;
  out[j * 5 + 4] = o4;
  out[N * 5 + j] = keep ? 1.0f : 0.0f;
}

// ---------------------------------------------------------------------------
extern "C" void kernel_launch(void* const* d_in, const int* in_sizes, int n_in,
                              void* d_out, int out_size, void* d_ws, size_t ws_size,
                              hipStream_t stream) {
  const float* boxes = (const float*)d_in[0];
  const float* scores = (const float*)d_in[1];
  const int* num_models = (const int*)d_in[2];
  float* out = (float*)d_out;

  char* p = (char*)d_ws;
  auto take = [&](size_t bytes) {
    char* r = p;
    p += (bytes + 255) & ~(size_t)255;
    return r;
  };
  int* rankpart = (int*)take((size_t)8 * N * 4);
  float* bx1s = (float*)take((size_t)N * 4);
  float* by1s = (float*)take((size_t)N * 4);
  float* bx2s = (float*)take((size_t)N * 4);
  float* by2s = (float*)take((size_t)N * 4);
  float* ss   = (float*)take((size_t)N * 4);
  float* areas= (float*)take((size_t)N * 4);
  int* cluster= (int*)take((size_t)N * 4);
  int* cnt    = (int*)take((size_t)N * 4);
  float* prob = (float*)take((size_t)N * 4);
  u64* pk     = (u64*)take((size_t)N * 8);            // packed (y2max, ~first)
  u64* D      = (u64*)take((size_t)NT * 8);           // head bitmap
  u64* S      = (u64*)take((size_t)NT * 8);           // suppressed bitmap
  u64* mtile  = (u64*)take((size_t)NT * NT * 64 * 8); // 8 MiB tiled adjacency
  u64* mrow   = (u64*)take((size_t)N * NT * 8);       // 8 MiB row-major adjacency

  k_rank<<<dim3(N / 256, 8), 256, 0, stream>>>(scores, rankpart);
  k_scatter<<<N / 256, 256, 0, stream>>>(boxes, scores, rankpart,
                                         bx1s, by1s, bx2s, by2s, ss, areas,
                                         cnt, prob, pk, D, S);
  k_adj<<<NT * (NT + 1) / 2, 64, 0, stream>>>(bx1s, by1s, bx2s, by2s, areas, mtile, mrow);
  k_rounds<<<NT, 256, 0, stream>>>(mtile, D, S);
  k_fix<<<1, 64, 0, stream>>>(mrow, D, S);
  k_cluster<<<NT, 256, 0, stream>>>(mtile, D, ss, by2s, cluster, cnt, prob, pk);
  k_out<<<N / 256, 256, 0, stream>>>(cluster, bx1s, by1s, bx2s, by2s, cnt, prob, pk, num_models, out);
}